// Round 26
// baseline (654.330 us; speedup 1.0000x reference)
//
#include <hip/hip_runtime.h>
#include <hip/hip_bf16.h>

#define SELU_L 1.0507009873554805f
#define SELU_A 1.6732632423543772f

typedef float  floatx4 __attribute__((ext_vector_type(4)));
typedef short  bf16x8  __attribute__((ext_vector_type(8)));

__device__ __forceinline__ float selu(float x) {
    return x > 0.f ? SELU_L * x : SELU_L * SELU_A * (expf(x) - 1.f);
}
__device__ __forceinline__ float fast_rcp(float x) {
    return __builtin_amdgcn_rcpf(x);
}
__device__ __forceinline__ unsigned short bf16_rne(float f) {
    unsigned int u = __float_as_uint(f);
    u += 0x7fffu + ((u >> 16) & 1u);
    return (unsigned short)(u >> 16);
}
__device__ __forceinline__ void cvt4(const float4 v, ushort4& h, ushort4& l) {
    h.x = bf16_rne(v.x); h.y = bf16_rne(v.y); h.z = bf16_rne(v.z); h.w = bf16_rne(v.w);
    float4 hf = make_float4(__uint_as_float((unsigned)h.x << 16),
                            __uint_as_float((unsigned)h.y << 16),
                            __uint_as_float((unsigned)h.z << 16),
                            __uint_as_float((unsigned)h.w << 16));
    l.x = bf16_rne(v.x - hf.x); l.y = bf16_rne(v.y - hf.y);
    l.z = bf16_rne(v.z - hf.z); l.w = bf16_rne(v.w - hf.w);
}
__device__ __forceinline__ void cvt8v(const float4 v0, const float4 v1,
                                      bf16x8& h8, bf16x8& l8) {
    float f[8] = {v0.x, v0.y, v0.z, v0.w, v1.x, v1.y, v1.z, v1.w};
#pragma unroll
    for (int j = 0; j < 8; ++j) {
        const unsigned short h = bf16_rne(f[j]);
        const float hf = __uint_as_float((unsigned)h << 16);
        const unsigned short l = bf16_rne(f[j] - hf);
        h8[j] = (short)h;
        l8[j] = (short)l;
    }
}

#define TILE_USH 12800                 // 25*4*16*8
#define GPAD 136
#define XP 808

// ---------------- Kernel W: pack fc_w into fragment-order bf16 hi/lo tiles --
__global__ __launch_bounds__(256) void wpack(
    const float* __restrict__ w,
    ushort* __restrict__ wth, ushort* __restrict__ wtl,
    double* __restrict__ shards, double* __restrict__ denomsh)
{
    __shared__ ushort hl[100 * GPAD];
    __shared__ ushort ll[100 * GPAD];
    const int t    = threadIdx.x;
    const int tile = blockIdx.x;       // 0..7

    if (tile == 0) {
        for (int i = t; i < 8192; i += 256) shards[i] = 0.0;
        if (t < 64) denomsh[t] = 0.0;
    }
    {
        const int g = 98 + (t >> 7), u = t & 127;
        hl[g * GPAD + u] = 0;
        ll[g * GPAD + u] = 0;
    }
    const float* src = w + (size_t)tile * 16 * 784;
    for (int s = t; s < 1568; s += 256) {
        const int row = s / 98, k8 = s - row * 98;
        const float* p = src + row * 784 + k8 * 8;
        float4 v0 = *reinterpret_cast<const float4*>(p);
        float4 v1 = *reinterpret_cast<const float4*>(p + 4);
        bf16x8 h8, l8;
        cvt8v(v0, v1, h8, l8);
        const int off = k8 * GPAD + row * 8;
        *reinterpret_cast<bf16x8*>(hl + off) = h8;
        *reinterpret_cast<bf16x8*>(ll + off) = l8;
    }
    __syncthreads();
    ushort* dh = wth + (size_t)tile * TILE_USH;
    ushort* dl = wtl + (size_t)tile * TILE_USH;
    for (int i = t; i < 1600; i += 256) {
        const int g = i >> 4, u = i & 15;
        const int src_off = g * GPAD + u * 8;
        *reinterpret_cast<uint4*>(dh + i * 8) =
            *reinterpret_cast<const uint4*>(hl + src_off);
        *reinterpret_cast<uint4*>(dl + i * 8) =
            *reinterpret_cast<const uint4*>(ll + src_off);
    }
}

// ---------------- Kernel A: direct-x MFMA GEMM  *** FULL-BODY x32 PROBE *** -
__global__ __launch_bounds__(256) void gemm1_direct_stats(
    const float* __restrict__ x,
    const ushort* __restrict__ wth, const ushort* __restrict__ wtl,
    const float* __restrict__ b, float* __restrict__ o1,
    double* __restrict__ shards)
{
    __shared__ ushort xh[16 * XP];
    __shared__ ushort xl[16 * XP];

    const int t    = threadIdx.x;
    const int wv   = t >> 6;
    const int lane = t & 63;
    const int lr   = lane & 15;
    const int lk   = lane >> 4;
    const int rowbase = blockIdx.x * 16;

    const float* src = x + (size_t)rowbase * 784;
    const int ct0 = wv * 2;
    const ushort* ah0 = xh + lr * XP + lk * 8;
    const ushort* al0 = xl + lr * XP + lk * 8;
    const ushort* bh0 = wth + (size_t)ct0 * TILE_USH + lane * 8;
    const ushort* bl0 = wtl + (size_t)ct0 * TILE_USH + lane * 8;
    const ushort* bh1 = wth + (size_t)(ct0 + 1) * TILE_USH + lane * 8;
    const ushort* bl1 = wtl + (size_t)(ct0 + 1) * TILE_USH + lane * 8;

    floatx4 acc0 = {}, acc1 = {};
#pragma unroll 1
    for (int rep = 0; rep < 32; ++rep) {
        int zo = 0;
        asm volatile("" : "+v"(zo));          // opaque zero: defeat hoist/DCE
        // ---- stage (idempotent, re-executed to measure its true cost)
        for (int i = t + zo; i < 3136; i += 256) {
            const int row = i / 196, seg = i - row * 196;
            float4 v = *reinterpret_cast<const float4*>(src + (size_t)row * 784 + seg * 4);
            ushort4 h, l;
            cvt4(v, h, l);
            *reinterpret_cast<ushort4*>(xh + row * XP + seg * 4) = h;
            *reinterpret_cast<ushort4*>(xl + row * XP + seg * 4) = l;
        }
        if (t < 32) {
            const int row = t >> 1, half = t & 1;
            const uint4 z = make_uint4(0, 0, 0, 0);
            *reinterpret_cast<uint4*>(xh + row * XP + 784 + half * 8) = z;
            *reinterpret_cast<uint4*>(xl + row * XP + 784 + half * 8) = z;
        }
        __syncthreads();
        // ---- K-loop
#pragma unroll 5
        for (int ks = 0; ks < 25; ++ks) {
            const int lo = ks * 32 + zo;
            const int go = ks * 512 + zo;
            bf16x8 Ah = *reinterpret_cast<const bf16x8*>(ah0 + lo);
            bf16x8 Al = *reinterpret_cast<const bf16x8*>(al0 + lo);
            bf16x8 B0h = *reinterpret_cast<const bf16x8*>(bh0 + go);
            bf16x8 B0l = *reinterpret_cast<const bf16x8*>(bl0 + go);
            bf16x8 B1h = *reinterpret_cast<const bf16x8*>(bh1 + go);
            bf16x8 B1l = *reinterpret_cast<const bf16x8*>(bl1 + go);
            acc0 = __builtin_amdgcn_mfma_f32_16x16x32_bf16(Al, B0h, acc0, 0, 0, 0);
            acc0 = __builtin_amdgcn_mfma_f32_16x16x32_bf16(Ah, B0l, acc0, 0, 0, 0);
            acc0 = __builtin_amdgcn_mfma_f32_16x16x32_bf16(Ah, B0h, acc0, 0, 0, 0);
            acc1 = __builtin_amdgcn_mfma_f32_16x16x32_bf16(Al, B1h, acc1, 0, 0, 0);
            acc1 = __builtin_amdgcn_mfma_f32_16x16x32_bf16(Ah, B1l, acc1, 0, 0, 0);
            acc1 = __builtin_amdgcn_mfma_f32_16x16x32_bf16(Ah, B1h, acc1, 0, 0, 0);
        }
        __syncthreads();
    }

    const int shard = blockIdx.x & 31;
#pragma unroll
    for (int c = 0; c < 2; ++c) {
        const floatx4 acc = c ? acc1 : acc0;
        const int col = (ct0 + c) * 16 + lr;
        const float bias = b[col];
        float s = 0.f, s2 = 0.f;
#pragma unroll
        for (int j = 0; j < 4; ++j) {
            const int row = rowbase + lk * 4 + j;
            const float val = selu(acc[j] * 0.03125f + bias);
            o1[(size_t)row * 128 + col] = val;
            s += val;
            s2 = fmaf(val, val, s2);
        }
        s  += __shfl_xor(s, 16);   s  += __shfl_xor(s, 32);
        s2 += __shfl_xor(s2, 16);  s2 += __shfl_xor(s2, 32);
        if (lane < 16) {
            atomicAdd(&shards[(size_t)shard * 128 + col],        (double)s);
            atomicAdd(&shards[4096 + (size_t)shard * 128 + col], (double)s2);
        }
    }
}

// ---------------- Kernel C: fold + BN + fc2  *** FULL-BODY x32 PROBE *** ----
__global__ __launch_bounds__(256) void bn_fc2_fold(
    const float* __restrict__ o1, const double* __restrict__ shards,
    const float* __restrict__ gamma, const float* __restrict__ beta,
    const float* __restrict__ fc2w, const float* __restrict__ fc2b,
    float* __restrict__ o_out, float4* __restrict__ packed)
{
    __shared__ double fs[256];
    __shared__ float sa[128], sb[128], w0[128], w1[128];
    const int t = threadIdx.x;

#pragma unroll 1
    for (int rep = 0; rep < 32; ++rep) {
        int zo = 0;
        asm volatile("" : "+v"(zo));          // opaque zero
        {
            const int which = t >> 7, col = (t & 127) + zo;
            const double* p = shards + (size_t)which * 4096 + col;
            double a = 0.0;
#pragma unroll
            for (int s = 0; s < 32; ++s) a += p[s * 128];
            fs[t] = a;
        }
        __syncthreads();
        if (t < 128) {
            const float mu  = (float)(fs[t]       * (1.0 / 8192.0));
            const float ex2 = (float)(fs[128 + t] * (1.0 / 8192.0));
            const float var = ex2 - mu * mu;
            const float inv = rsqrtf(var + 1e-5f);
            const float g   = gamma[t] * inv;
            sa[t] = g;
            sb[t] = beta[t] - mu * g;
            w0[t] = fc2w[t];
            w1[t] = fc2w[128 + t];
        }
        __syncthreads();

        const int wv   = t >> 6;
        const int lane = t & 63;
        const float b0 = fc2b[0], b1 = fc2b[1];
#pragma unroll
        for (int i = 0; i < 4; ++i) {
            const int row = blockIdx.x * 16 + wv * 4 + i + zo;
            const int c0 = lane, c1 = lane + 64;
            const float v0 = o1[(size_t)row * 128 + c0] * sa[c0] + sb[c0];
            const float v1 = o1[(size_t)row * 128 + c1] * sa[c1] + sb[c1];
            float d0 = v0 * w0[c0] + v1 * w0[c1];
            float d1 = v0 * w1[c0] + v1 * w1[c1];
#pragma unroll
            for (int off = 32; off >= 1; off >>= 1) {
                d0 += __shfl_down(d0, off);
                d1 += __shfl_down(d1, off);
            }
            if (lane == 0) {
                const float y0 = selu(d0 + b0);
                const float y1 = selu(d1 + b1);
                o_out[(size_t)row * 2 + 0] = y0;
                o_out[(size_t)row * 2 + 1] = y1;
                packed[row] = make_float4(y0, y1, y0 * y0 + y1 * y1, 0.f);
            }
        }
        __syncthreads();
    }
}

// ---------------- Kernel D: TRIANGLE denom (R24 verbatim) -------------------
__global__ __launch_bounds__(256) void denom_tri(
    const float4* __restrict__ packed, double* __restrict__ denomsh)
{
    const int rb = blockIdx.x * 32;
    const int cb = blockIdx.y * 1024;
    if (cb + 1024 <= rb) return;               // no pair with j > i

    const int t = threadIdx.x;
    const bool upper = (cb >= rb + 32);        // every col > every row

    float4 cd0 = packed[cb + t];
    float4 cd1 = packed[cb + t + 256];
    float4 cd2 = packed[cb + t + 512];
    float4 cd3 = packed[cb + t + 768];

    float a0 = 0.f, a1 = 0.f, a2 = 0.f, a3 = 0.f;
    if (upper) {
#pragma unroll 8
        for (int r = 0; r < 32; ++r) {
            const float4 pi = packed[rb + r];  // uniform -> scalar load
            const float u = 1.f + pi.z;
            float v0 = fmaxf(fmaf(-2.f, fmaf(pi.x, cd0.x, pi.y * cd0.y), u + cd0.z), 1.f);
            float v1 = fmaxf(fmaf(-2.f, fmaf(pi.x, cd1.x, pi.y * cd1.y), u + cd1.z), 1.f);
            float v2 = fmaxf(fmaf(-2.f, fmaf(pi.x, cd2.x, pi.y * cd2.y), u + cd2.z), 1.f);
            float v3 = fmaxf(fmaf(-2.f, fmaf(pi.x, cd3.x, pi.y * cd3.y), u + cd3.z), 1.f);
            a0 += fast_rcp(v0);
            a1 += fast_rcp(v1);
            a2 += fast_rcp(v2);
            a3 += fast_rcp(v3);
        }
    } else {                                    // diagonal straddle: predicate
        const int c0 = cb + t, c1 = c0 + 256, c2 = c0 + 512, c3 = c0 + 768;
#pragma unroll 4
        for (int r = 0; r < 32; ++r) {
            const int i = rb + r;
            const float4 pi = packed[i];
            const float u = 1.f + pi.z;
            float v0 = fmaxf(fmaf(-2.f, fmaf(pi.x, cd0.x, pi.y * cd0.y), u + cd0.z), 1.f);
            float v1 = fmaxf(fmaf(-2.f, fmaf(pi.x, cd1.x, pi.y * cd1.y), u + cd1.z), 1.f);
            float v2 = fmaxf(fmaf(-2.f, fmaf(pi.x, cd2.x, pi.y * cd2.y), u + cd2.z), 1.f);
            float v3 = fmaxf(fmaf(-2.f, fmaf(pi.x, cd3.x, pi.y * cd3.y), u + cd3.z), 1.f);
            a0 += (c0 > i) ? fast_rcp(v0) : 0.f;
            a1 += (c1 > i) ? fast_rcp(v1) : 0.f;
            a2 += (c2 > i) ? fast_rcp(v2) : 0.f;
            a3 += (c3 > i) ? fast_rcp(v3) : 0.f;
        }
    }
    float accf = (a0 + a1) + (a2 + a3);
#pragma unroll
    for (int off = 32; off >= 1; off >>= 1) accf += __shfl_down(accf, off);
    __shared__ double wsum[4];
    const int wv = t >> 6, lane = t & 63;
    if (lane == 0) wsum[wv] = (double)accf;
    __syncthreads();
    if (t == 0)
        atomicAdd(&denomsh[(blockIdx.x * 8 + blockIdx.y) & 63],
                  wsum[0] + wsum[1] + wsum[2] + wsum[3]);
}

// ---------------- Kernel E: qij write, slab layout (at write floor) ---------
__global__ __launch_bounds__(512) void qij_write_slab(
    const float4* __restrict__ packed, const double* __restrict__ denomsh,
    float* __restrict__ qij)
{
    const int t  = threadIdx.x;              // 0..511
    const int rb = blockIdx.x * 16;

    double tot = 0.0;
#pragma unroll
    for (int s = 0; s < 64; ++s) tot += denomsh[s];
    const float inv = (float)(1.0 / (2.0 * tot));      // denom = 2 * S_tri

    float4 cd[4][4];
#pragma unroll
    for (int c = 0; c < 4; ++c)
#pragma unroll
        for (int u = 0; u < 4; ++u)
            cd[c][u] = packed[c * 2048 + t * 4 + u];

#pragma unroll 2
    for (int r = 0; r < 16; ++r) {
        const int j = rb + r;
        const float4 pi = packed[j];
        float* outrow = qij + (size_t)j * 8192 + t * 4;
#pragma unroll
        for (int c = 0; c < 4; ++c) {
            floatx4 q;
#pragma unroll
            for (int u = 0; u < 4; ++u) {
                float dis = pi.z + cd[c][u].z
                          - 2.f * fmaf(pi.x, cd[c][u].x, pi.y * cd[c][u].y);
                dis = fmaxf(dis, 0.f);
                q[u] = inv * fast_rcp(1.f + dis);
            }
            *reinterpret_cast<floatx4*>(outrow + c * 2048) = q;
        }
    }
}

// ---------------------------------------------------------------------------
extern "C" void kernel_launch(void* const* d_in, const int* in_sizes, int n_in,
                              void* d_out, int out_size, void* d_ws, size_t ws_size,
                              hipStream_t stream)
{
    const float* x      = (const float*)d_in[0];
    const float* fc_w   = (const float*)d_in[1];
    const float* fc_b   = (const float*)d_in[2];
    const float* gamma  = (const float*)d_in[3];
    const float* beta   = (const float*)d_in[4];
    const float* fc2_w  = (const float*)d_in[5];
    const float* fc2_b  = (const float*)d_in[6];

    constexpr int N = 8192;

    float* qij   = (float*)d_out;                          // [N, N]
    float* o_out = (float*)d_out + (size_t)N * N;          // [N, 2]

    char* ws = (char*)d_ws;
    constexpr size_t O1_OFF     = 0;                          // 4 MB
    constexpr size_t DSH_OFF    = (size_t)N * 128 * 4;        // 64 doubles
    constexpr size_t SH_OFF     = DSH_OFF + 4096;             // 8192 doubles
    constexpr size_t PACKED_OFF = SH_OFF + 65536;             // 128 KB
    constexpr size_t WTH_OFF    = PACKED_OFF + (size_t)N * 16;
    constexpr size_t WT_B       = (size_t)8 * TILE_USH * 2;   // 204.8 KB
    constexpr size_t WTL_OFF    = WTH_OFF + WT_B;

    float*  o1      = (float*)(ws + O1_OFF);
    double* denomsh = (double*)(ws + DSH_OFF);             // [64]
    double* shards  = (double*)(ws + SH_OFF);              // [2][32][128]
    float4* packed  = (float4*)(ws + PACKED_OFF);
    ushort* wth     = (ushort*)(ws + WTH_OFF);
    ushort* wtl     = (ushort*)(ws + WTL_OFF);

    // W: pack fc_w into fragment-order tiles; zero shards + denom shards
    wpack<<<8, 256, 0, stream>>>(fc_w, wth, wtl, shards, denomsh);

    // A: direct-x MFMA GEMM  [full-body x32 probe]
    gemm1_direct_stats<<<512, 256, 0, stream>>>(x, wth, wtl, fc_b, o1, shards);

    // C: fold shards + BN + fc2  [full-body x32 probe]
    bn_fc2_fold<<<512, 256, 0, stream>>>(o1, shards, gamma, beta, fc2_w, fc2_b, o_out, packed);

    // D: triangle denom (R24 verbatim)
    denom_tri<<<dim3(N / 32, N / 1024), 256, 0, stream>>>(packed, denomsh);

    // E: qij write (known: 38.8 us, at write floor)
    qij_write_slab<<<512, 512, 0, stream>>>(packed, denomsh, qij);
}

// Round 27
// 90.697 us; speedup vs baseline: 7.2145x; 7.2145x over previous
//
#include <hip/hip_runtime.h>
#include <hip/hip_bf16.h>

#define SELU_L 1.0507009873554805f
#define SELU_A 1.6732632423543772f

typedef float  floatx4 __attribute__((ext_vector_type(4)));
typedef short  bf16x8  __attribute__((ext_vector_type(8)));

__device__ __forceinline__ float selu(float x) {
    return x > 0.f ? SELU_L * x : SELU_L * SELU_A * (expf(x) - 1.f);
}
__device__ __forceinline__ float fast_rcp(float x) {
    return __builtin_amdgcn_rcpf(x);
}
__device__ __forceinline__ unsigned short bf16_rne(float f) {
    unsigned int u = __float_as_uint(f);
    u += 0x7fffu + ((u >> 16) & 1u);
    return (unsigned short)(u >> 16);
}
__device__ __forceinline__ ushort4 rne4(const float4 v) {
    ushort4 h;
    h.x = bf16_rne(v.x); h.y = bf16_rne(v.y);
    h.z = bf16_rne(v.z); h.w = bf16_rne(v.w);
    return h;
}

#define TILE_USH 12800                 // 25*4*16*8
#define GPAD 136
#define XP 808

// ---------------- Kernel W: pack fc_w into fragment-order bf16 tiles --------
// Single plane (bf16 rne). 8 blocks; block 0 zeroes shards + denom shards.
__global__ __launch_bounds__(256) void wpack(
    const float* __restrict__ w, ushort* __restrict__ wth,
    double* __restrict__ shards, double* __restrict__ denomsh)
{
    __shared__ ushort hl[100 * GPAD];
    const int t    = threadIdx.x;
    const int tile = blockIdx.x;       // 0..7

    if (tile == 0) {
        for (int i = t; i < 8192; i += 256) shards[i] = 0.0;
        if (t < 64) denomsh[t] = 0.0;
    }
    {
        const int g = 98 + (t >> 7), u = t & 127;
        hl[g * GPAD + u] = 0;
    }
    const float* src = w + (size_t)tile * 16 * 784;
    for (int s = t; s < 1568; s += 256) {
        const int row = s / 98, k8 = s - row * 98;
        const float* p = src + row * 784 + k8 * 8;
        ushort4 h0 = rne4(*reinterpret_cast<const float4*>(p));
        ushort4 h1 = rne4(*reinterpret_cast<const float4*>(p + 4));
        const int off = k8 * GPAD + row * 8;
        *reinterpret_cast<ushort4*>(hl + off)     = h0;
        *reinterpret_cast<ushort4*>(hl + off + 4) = h1;
    }
    __syncthreads();
    ushort* dh = wth + (size_t)tile * TILE_USH;
    for (int i = t; i < 1600; i += 256) {
        const int g = i >> 4, u = i & 15;
        *reinterpret_cast<uint4*>(dh + i * 8) =
            *reinterpret_cast<const uint4*>(hl + g * GPAD + u * 8);
    }
}

// ---------------- Kernel A: single-plane bf16 MFMA GEMM ---------------------
// 512 blocks x 512 threads (8 waves -> 4 waves/SIMD). Block = 16 x-rows
// staged once (coalesced fp32 -> bf16, 25.9 KB LDS). Wave wv -> ct = wv.
// 25 branch-free K-steps, 1 MFMA each. Sharded column stats.
__global__ __launch_bounds__(512) void gemm1_direct_stats(
    const float* __restrict__ x, const ushort* __restrict__ wth,
    const float* __restrict__ b, float* __restrict__ o1,
    double* __restrict__ shards)
{
    __shared__ ushort xh[16 * XP];

    const int t    = threadIdx.x;
    const int wv   = t >> 6;           // 0..7
    const int lane = t & 63;
    const int lr   = lane & 15;
    const int lk   = lane >> 4;
    const int rowbase = blockIdx.x * 16;

    // ---- stage 16 rows x 784 fp32 -> bf16, coalesced
    const float* src = x + (size_t)rowbase * 784;
    for (int i = t; i < 3136; i += 512) {
        const int row = i / 196, seg = i - row * 196;
        float4 v = *reinterpret_cast<const float4*>(src + (size_t)row * 784 + seg * 4);
        *reinterpret_cast<ushort4*>(xh + row * XP + seg * 4) = rne4(v);
    }
    if (t < 32) {                      // zero-pad k 784..799
        const int row = t >> 1, half = t & 1;
        const uint4 z = make_uint4(0, 0, 0, 0);
        *reinterpret_cast<uint4*>(xh + row * XP + 784 + half * 8) = z;
    }
    __syncthreads();

    // ---- compute: wave wv owns ct = wv (cols wv*16 .. wv*16+15)
    const ushort* ah = xh + lr * XP + lk * 8;
    const ushort* bh = wth + (size_t)wv * TILE_USH + lane * 8;

    floatx4 acc = {};
#pragma unroll 5
    for (int ks = 0; ks < 25; ++ks) {
        bf16x8 Ah = *reinterpret_cast<const bf16x8*>(ah + ks * 32);
        bf16x8 Bh = *reinterpret_cast<const bf16x8*>(bh + ks * 512);
        acc = __builtin_amdgcn_mfma_f32_16x16x32_bf16(Ah, Bh, acc, 0, 0, 0);
    }

    // ---- epilogue: bias + selu + o1 + sharded stats
    const int col  = wv * 16 + lr;
    const float bias = b[col];
    float s = 0.f, s2 = 0.f;
#pragma unroll
    for (int j = 0; j < 4; ++j) {
        const int row = rowbase + lk * 4 + j;
        const float val = selu(acc[j] + bias);
        o1[(size_t)row * 128 + col] = val;
        s += val;
        s2 = fmaf(val, val, s2);
    }
    s  += __shfl_xor(s, 16);   s  += __shfl_xor(s, 32);
    s2 += __shfl_xor(s2, 16);  s2 += __shfl_xor(s2, 32);
    const int shard = blockIdx.x & 31;
    if (lane < 16) {
        atomicAdd(&shards[(size_t)shard * 128 + col],        (double)s);
        atomicAdd(&shards[4096 + (size_t)shard * 128 + col], (double)s2);
    }
}

// ---------------- Kernel C: fold shards + BN + fc2 + selu (512 blocks) ------
__global__ __launch_bounds__(256) void bn_fc2_fold(
    const float* __restrict__ o1, const double* __restrict__ shards,
    const float* __restrict__ gamma, const float* __restrict__ beta,
    const float* __restrict__ fc2w, const float* __restrict__ fc2b,
    float* __restrict__ o_out, float4* __restrict__ packed)
{
    __shared__ double fs[256];
    __shared__ float sa[128], sb[128], w0[128], w1[128];
    const int t = threadIdx.x;

    {
        const int which = t >> 7, col = t & 127;
        const double* p = shards + (size_t)which * 4096 + col;
        double a = 0.0;
#pragma unroll
        for (int s = 0; s < 32; ++s) a += p[s * 128];
        fs[t] = a;
    }
    __syncthreads();
    if (t < 128) {
        const float mu  = (float)(fs[t]       * (1.0 / 8192.0));
        const float ex2 = (float)(fs[128 + t] * (1.0 / 8192.0));
        const float var = ex2 - mu * mu;
        const float inv = rsqrtf(var + 1e-5f);
        const float g   = gamma[t] * inv;
        sa[t] = g;
        sb[t] = beta[t] - mu * g;
        w0[t] = fc2w[t];
        w1[t] = fc2w[128 + t];
    }
    __syncthreads();

    const int wv   = t >> 6;
    const int lane = t & 63;
    const float b0 = fc2b[0], b1 = fc2b[1];
#pragma unroll
    for (int i = 0; i < 4; ++i) {
        const int row = blockIdx.x * 16 + wv * 4 + i;
        const int c0 = lane, c1 = lane + 64;
        const float v0 = o1[(size_t)row * 128 + c0] * sa[c0] + sb[c0];
        const float v1 = o1[(size_t)row * 128 + c1] * sa[c1] + sb[c1];
        float d0 = v0 * w0[c0] + v1 * w0[c1];
        float d1 = v0 * w1[c0] + v1 * w1[c1];
#pragma unroll
        for (int off = 32; off >= 1; off >>= 1) {
            d0 += __shfl_down(d0, off);
            d1 += __shfl_down(d1, off);
        }
        if (lane == 0) {
            const float y0 = selu(d0 + b0);
            const float y1 = selu(d1 + b1);
            o_out[(size_t)row * 2 + 0] = y0;
            o_out[(size_t)row * 2 + 1] = y1;
            packed[row] = make_float4(y0, y1, y0 * y0 + y1 * y1, 0.f);
        }
    }
}

// ---------------- Kernel D: TRIANGLE denom (R24 verbatim) -------------------
__global__ __launch_bounds__(256) void denom_tri(
    const float4* __restrict__ packed, double* __restrict__ denomsh)
{
    const int rb = blockIdx.x * 32;
    const int cb = blockIdx.y * 1024;
    if (cb + 1024 <= rb) return;               // no pair with j > i

    const int t = threadIdx.x;
    const bool upper = (cb >= rb + 32);        // every col > every row

    float4 cd0 = packed[cb + t];
    float4 cd1 = packed[cb + t + 256];
    float4 cd2 = packed[cb + t + 512];
    float4 cd3 = packed[cb + t + 768];

    float a0 = 0.f, a1 = 0.f, a2 = 0.f, a3 = 0.f;
    if (upper) {
#pragma unroll 8
        for (int r = 0; r < 32; ++r) {
            const float4 pi = packed[rb + r];  // uniform -> scalar load
            const float u = 1.f + pi.z;
            float v0 = fmaxf(fmaf(-2.f, fmaf(pi.x, cd0.x, pi.y * cd0.y), u + cd0.z), 1.f);
            float v1 = fmaxf(fmaf(-2.f, fmaf(pi.x, cd1.x, pi.y * cd1.y), u + cd1.z), 1.f);
            float v2 = fmaxf(fmaf(-2.f, fmaf(pi.x, cd2.x, pi.y * cd2.y), u + cd2.z), 1.f);
            float v3 = fmaxf(fmaf(-2.f, fmaf(pi.x, cd3.x, pi.y * cd3.y), u + cd3.z), 1.f);
            a0 += fast_rcp(v0);
            a1 += fast_rcp(v1);
            a2 += fast_rcp(v2);
            a3 += fast_rcp(v3);
        }
    } else {                                    // diagonal straddle: predicate
        const int c0 = cb + t, c1 = c0 + 256, c2 = c0 + 512, c3 = c0 + 768;
#pragma unroll 4
        for (int r = 0; r < 32; ++r) {
            const int i = rb + r;
            const float4 pi = packed[i];
            const float u = 1.f + pi.z;
            float v0 = fmaxf(fmaf(-2.f, fmaf(pi.x, cd0.x, pi.y * cd0.y), u + cd0.z), 1.f);
            float v1 = fmaxf(fmaf(-2.f, fmaf(pi.x, cd1.x, pi.y * cd1.y), u + cd1.z), 1.f);
            float v2 = fmaxf(fmaf(-2.f, fmaf(pi.x, cd2.x, pi.y * cd2.y), u + cd2.z), 1.f);
            float v3 = fmaxf(fmaf(-2.f, fmaf(pi.x, cd3.x, pi.y * cd3.y), u + cd3.z), 1.f);
            a0 += (c0 > i) ? fast_rcp(v0) : 0.f;
            a1 += (c1 > i) ? fast_rcp(v1) : 0.f;
            a2 += (c2 > i) ? fast_rcp(v2) : 0.f;
            a3 += (c3 > i) ? fast_rcp(v3) : 0.f;
        }
    }
    float accf = (a0 + a1) + (a2 + a3);
#pragma unroll
    for (int off = 32; off >= 1; off >>= 1) accf += __shfl_down(accf, off);
    __shared__ double wsum[4];
    const int wv = t >> 6, lane = t & 63;
    if (lane == 0) wsum[wv] = (double)accf;
    __syncthreads();
    if (t == 0)
        atomicAdd(&denomsh[(blockIdx.x * 8 + blockIdx.y) & 63],
                  wsum[0] + wsum[1] + wsum[2] + wsum[3]);
}

// ---------------- Kernel E: qij write, slab layout (at write floor) ---------
__global__ __launch_bounds__(512) void qij_write_slab(
    const float4* __restrict__ packed, const double* __restrict__ denomsh,
    float* __restrict__ qij)
{
    const int t  = threadIdx.x;              // 0..511
    const int rb = blockIdx.x * 16;

    double tot = 0.0;
#pragma unroll
    for (int s = 0; s < 64; ++s) tot += denomsh[s];
    const float inv = (float)(1.0 / (2.0 * tot));      // denom = 2 * S_tri

    float4 cd[4][4];
#pragma unroll
    for (int c = 0; c < 4; ++c)
#pragma unroll
        for (int u = 0; u < 4; ++u)
            cd[c][u] = packed[c * 2048 + t * 4 + u];

#pragma unroll 2
    for (int r = 0; r < 16; ++r) {
        const int j = rb + r;
        const float4 pi = packed[j];
        float* outrow = qij + (size_t)j * 8192 + t * 4;
#pragma unroll
        for (int c = 0; c < 4; ++c) {
            floatx4 q;
#pragma unroll
            for (int u = 0; u < 4; ++u) {
                float dis = pi.z + cd[c][u].z
                          - 2.f * fmaf(pi.x, cd[c][u].x, pi.y * cd[c][u].y);
                dis = fmaxf(dis, 0.f);
                q[u] = inv * fast_rcp(1.f + dis);
            }
            *reinterpret_cast<floatx4*>(outrow + c * 2048) = q;
        }
    }
}

// ---------------------------------------------------------------------------
extern "C" void kernel_launch(void* const* d_in, const int* in_sizes, int n_in,
                              void* d_out, int out_size, void* d_ws, size_t ws_size,
                              hipStream_t stream)
{
    const float* x      = (const float*)d_in[0];
    const float* fc_w   = (const float*)d_in[1];
    const float* fc_b   = (const float*)d_in[2];
    const float* gamma  = (const float*)d_in[3];
    const float* beta   = (const float*)d_in[4];
    const float* fc2_w  = (const float*)d_in[5];
    const float* fc2_b  = (const float*)d_in[6];

    constexpr int N = 8192;

    float* qij   = (float*)d_out;                          // [N, N]
    float* o_out = (float*)d_out + (size_t)N * N;          // [N, 2]

    char* ws = (char*)d_ws;
    constexpr size_t O1_OFF     = 0;                          // 4 MB
    constexpr size_t DSH_OFF    = (size_t)N * 128 * 4;        // 64 doubles
    constexpr size_t SH_OFF     = DSH_OFF + 4096;             // 8192 doubles
    constexpr size_t PACKED_OFF = SH_OFF + 65536;             // 128 KB
    constexpr size_t WTH_OFF    = PACKED_OFF + (size_t)N * 16;

    float*  o1      = (float*)(ws + O1_OFF);
    double* denomsh = (double*)(ws + DSH_OFF);             // [64]
    double* shards  = (double*)(ws + SH_OFF);              // [2][32][128]
    float4* packed  = (float4*)(ws + PACKED_OFF);
    ushort* wth     = (ushort*)(ws + WTH_OFF);

    // W: pack fc_w into fragment-order bf16 tiles; zero shards + denom shards
    wpack<<<8, 256, 0, stream>>>(fc_w, wth, shards, denomsh);

    // A: single-plane bf16 MFMA GEMM + sharded stats
    gemm1_direct_stats<<<512, 512, 0, stream>>>(x, wth, fc_b, o1, shards);

    // C: fold shards + BN + fc2 + selu -> o_out, packed
    bn_fc2_fold<<<512, 256, 0, stream>>>(o1, shards, gamma, beta, fc2_w, fc2_b, o_out, packed);

    // D: triangle denom -> 64 shards
    denom_tri<<<dim3(N / 32, N / 1024), 256, 0, stream>>>(packed, denomsh);

    // E: qij = (1/(2*S_tri)) / (1 + dis)
    qij_write_slab<<<512, 512, 0, stream>>>(packed, denomsh, qij);
}